// Round 5
// baseline (16053.070 us; speedup 1.0000x reference)
//
#include <hip/hip_runtime.h>
#include <cstdint>
#include <cstddef>

// Problem constants
#define S_  4096   // sentence length / batch of positions
#define L_  16     // chars per word
#define E_  512    // embedding dim
#define H_  512    // hidden dim
#define G4_ 2048   // 4*H (gates)
#define T_  64     // tag count
#define WORD_WGS 32

__device__ __forceinline__ float sigmoidf_(float x) {
    return 1.0f / (1.0f + __expf(-x));
}
__device__ __forceinline__ float fast_tanhf_(float x) {
    // tanh(x) = 1 - 2/(exp(2x)+1); saturates correctly for |x| large
    return 1.0f - 2.0f / (__expf(2.0f * x) + 1.0f);
}

// ---------------------------------------------------------------------------
// Generic fp32 GEMM:  C[m,n] = sum_k A[m,k] * B[n,k]
// A row m, col k:  k <  Ksplit -> A1[gatherIdx(m)][k]    (row length Ksplit)
//                  k >= Ksplit -> A2[m][k-Ksplit]        (row length K-Ksplit)
// B row n, col k:  k <  Ksplit -> B1[n][k], else B2[n][k-Ksplit]
// Used for: word gx (gather word_emb, K=512), char step gates
// (gather char_emb | h concat, K=1024).
// Tiles: 128x128x16, 256 threads, 8x8 accumulators (2x2 of float4 subtiles).
// ---------------------------------------------------------------------------
#define BM 128
#define BN 128
#define BK 16

__global__ __launch_bounds__(256, 2)
void gemm_nt_kernel(const float* __restrict__ A1, const int* __restrict__ idxA,
                    int idxStride, int idxOff, const float* __restrict__ A2,
                    const float* __restrict__ B1, const float* __restrict__ B2,
                    int Ksplit, int K, int N, float* __restrict__ C)
{
    __shared__ float As[BK][BM + 4];   // [k][m], +4 pad: store-scatter 2-way max
    __shared__ float Bs[BK][BN + 4];   // [k][n]
    __shared__ int   rIdx[BM];

    const int tid = threadIdx.x;
    const int m0 = blockIdx.y * BM;
    const int n0 = blockIdx.x * BN;
    if (idxA && tid < BM)
        rIdx[tid] = idxA[(size_t)(m0 + tid) * idxStride + idxOff];

    const int tx = tid & 15;      // 0..15 (n micro)
    const int ty = tid >> 4;      // 0..15 (m micro)
    const int ar = tid >> 2;      // 0..63 staging row
    const int aq = tid & 3;       // staging quad (4 floats)

    float acc[8][8];
#pragma unroll
    for (int i = 0; i < 8; ++i)
#pragma unroll
        for (int j = 0; j < 8; ++j) acc[i][j] = 0.f;

    for (int k0 = 0; k0 < K; k0 += BK) {
        __syncthreads();   // also covers rIdx on the first iteration
        const bool firstHalf = (k0 < Ksplit);
        const int  kk0 = firstHalf ? k0 : (k0 - Ksplit);
#pragma unroll
        for (int part = 0; part < 2; ++part) {
            const int row = ar + part * 64;
            float4 av, bv;
            if (firstHalf) {
                const int grA = idxA ? rIdx[row] : (m0 + row);
                av = *(const float4*)(A1 + (size_t)grA * Ksplit + kk0 + aq * 4);
                bv = *(const float4*)(B1 + (size_t)(n0 + row) * Ksplit + kk0 + aq * 4);
            } else {
                const int Kr = K - Ksplit;
                av = *(const float4*)(A2 + (size_t)(m0 + row) * Kr + kk0 + aq * 4);
                bv = *(const float4*)(B2 + (size_t)(n0 + row) * Kr + kk0 + aq * 4);
            }
            As[aq * 4 + 0][row] = av.x; As[aq * 4 + 1][row] = av.y;
            As[aq * 4 + 2][row] = av.z; As[aq * 4 + 3][row] = av.w;
            Bs[aq * 4 + 0][row] = bv.x; Bs[aq * 4 + 1][row] = bv.y;
            Bs[aq * 4 + 2][row] = bv.z; Bs[aq * 4 + 3][row] = bv.w;
        }
        __syncthreads();
#pragma unroll
        for (int kk = 0; kk < BK; ++kk) {
            const float4 a0 = *(const float4*)&As[kk][ty * 4];
            const float4 a1 = *(const float4*)&As[kk][64 + ty * 4];
            const float4 b0 = *(const float4*)&Bs[kk][tx * 4];
            const float4 b1 = *(const float4*)&Bs[kk][64 + tx * 4];
            const float a[8] = {a0.x, a0.y, a0.z, a0.w, a1.x, a1.y, a1.z, a1.w};
            const float b[8] = {b0.x, b0.y, b0.z, b0.w, b1.x, b1.y, b1.z, b1.w};
#pragma unroll
            for (int i = 0; i < 8; ++i)
#pragma unroll
                for (int j = 0; j < 8; ++j)
                    acc[i][j] = fmaf(a[i], b[j], acc[i][j]);
        }
    }
#pragma unroll
    for (int ri = 0; ri < 2; ++ri)
#pragma unroll
        for (int i = 0; i < 4; ++i) {
            const int m = m0 + ri * 64 + ty * 4 + i;
            float4 v0 = make_float4(acc[ri * 4 + i][0], acc[ri * 4 + i][1],
                                    acc[ri * 4 + i][2], acc[ri * 4 + i][3]);
            float4 v1 = make_float4(acc[ri * 4 + i][4], acc[ri * 4 + i][5],
                                    acc[ri * 4 + i][6], acc[ri * 4 + i][7]);
            *(float4*)(C + (size_t)m * N + n0 + tx * 4)      = v0;
            *(float4*)(C + (size_t)m * N + n0 + 64 + tx * 4) = v1;
        }
}

// ---------------------------------------------------------------------------
// Word LSTM: batch=1, 4096 sequential steps. 32 persistent workgroups, each
// owns 16 hidden units (64 gate rows of Whh held in REGISTERS: 64 f32/thread).
// Per-step cross-wg sync via per-step atomic counters (agent scope).
// h published with agent-scope atomic stores (bypass non-coherent per-XCD L2).
// Safety argument: 32 wgs x 8 waves (~100 VGPR/wave, tiny LDS) -> all blocks
// dispatch immediately on 256 CUs; co-residency guaranteed.
// Buffer rotation hazard: a wg entering step t+2 (writes buf[(t+1)&1]) must
// have passed barrier t+1, which happens-after every wg's step-t read of
// buf[(t+1)&1]. No overlap.
// ---------------------------------------------------------------------------
__global__ __launch_bounds__(512)
void word_lstm_kernel(const float* __restrict__ gxw, const float* __restrict__ Whh,
                      const float* __restrict__ bih, const float* __restrict__ bhh,
                      float* __restrict__ hsw, float* __restrict__ h_buf,
                      unsigned int* __restrict__ cnt, int T)
{
    const int wg   = blockIdx.x;          // 0..31
    const int base = wg * 16;             // hidden slice [base, base+16)
    const int tid  = threadIdx.x;         // 0..511
    const int r    = tid >> 3;            // local gate row 0..63
    const int p    = tid & 7;             // 8-way split of the 512-dot
    // local row ordering: r<16 -> i gates, 16..31 -> f, 32..47 -> g, 48..63 -> o
    const int grow = (r >> 4) * 512 + base + (r & 15);

    // Whh slice in registers: thread covers float4 columns c4 = kk*8 + p
    float4 w[16];
    const float4* Wrow = (const float4*)(Whh + (size_t)grow * 512);
#pragma unroll
    for (int kk = 0; kk < 16; ++kk) w[kk] = Wrow[kk * 8 + p];

    __shared__ float h_lds[512];
    __shared__ float gate_lds[64];
    __shared__ float bsum[64];
    if (tid < 64) {
        const int gr = (tid >> 4) * 512 + base + (tid & 15);
        bsum[tid] = bih[gr] + bhh[gr];
    }
    if (tid < 128) ((float4*)h_lds)[tid] = make_float4(0.f, 0.f, 0.f, 0.f); // h0 = 0
    float cstate = 0.f;                                                      // c0 = 0
    __syncthreads();

    for (int t = 0; t < T; ++t) {
        // prefetch gx early to hide latency under the matvec
        float gxv = 0.f;
        if (p == 0) gxv = gxw[(size_t)t * G4_ + grow];

        float s = 0.f;
#pragma unroll
        for (int kk = 0; kk < 16; ++kk) {
            const float4 h4 = ((const float4*)h_lds)[kk * 8 + p];
            s = fmaf(w[kk].x, h4.x, s);
            s = fmaf(w[kk].y, h4.y, s);
            s = fmaf(w[kk].z, h4.z, s);
            s = fmaf(w[kk].w, h4.w, s);
        }
        s += __shfl_xor(s, 1);
        s += __shfl_xor(s, 2);
        s += __shfl_xor(s, 4);
        if (p == 0) gate_lds[r] = s + gxv + bsum[r];
        __syncthreads();

        if (tid < 16) {
            const float gi = gate_lds[tid];
            const float gf = gate_lds[16 + tid];
            const float gg = gate_lds[32 + tid];
            const float go = gate_lds[48 + tid];
            const float cn = sigmoidf_(gf) * cstate + sigmoidf_(gi) * fast_tanhf_(gg);
            cstate = cn;
            const float hn = sigmoidf_(go) * fast_tanhf_(cn);
            hsw[(size_t)t * H_ + base + tid] = hn;
            __hip_atomic_store(&h_buf[((t + 1) & 1) * H_ + base + tid], hn,
                               __ATOMIC_RELAXED, __HIP_MEMORY_SCOPE_AGENT);
        }
        __syncthreads();   // drains vmcnt: h stores device-visible before release

        if (tid == 0) {
            __hip_atomic_fetch_add(&cnt[t], 1u, __ATOMIC_RELEASE, __HIP_MEMORY_SCOPE_AGENT);
            while (__hip_atomic_load(&cnt[t], __ATOMIC_ACQUIRE, __HIP_MEMORY_SCOPE_AGENT)
                   < (unsigned)WORD_WGS)
                __builtin_amdgcn_s_sleep(2);
        }
        __syncthreads();

        // reload full h for next step (agent-scope loads: fresh data)
        {
            const float* src = h_buf + ((t + 1) & 1) * H_;
            h_lds[tid] = __hip_atomic_load(&src[tid], __ATOMIC_RELAXED,
                                           __HIP_MEMORY_SCOPE_AGENT);
        }
        __syncthreads();
    }
}

// ---------------------------------------------------------------------------
// Char LSTM elementwise step: gates -> (h, c, out_sum) with length mask.
// One thread per (s, 4 hidden units).
// ---------------------------------------------------------------------------
__global__ __launch_bounds__(256)
void char_update_kernel(const float* __restrict__ gates,
                        const float* __restrict__ bih, const float* __restrict__ bhh,
                        const int* __restrict__ lengths, int l,
                        float* __restrict__ h, float* __restrict__ c,
                        float* __restrict__ osum)
{
    const int gid = blockIdx.x * blockDim.x + threadIdx.x;  // 0 .. 4096*128-1
    const int s  = gid >> 7;
    const int j4 = (gid & 127) * 4;
    const bool valid = (l < lengths[s]);

    const float4 gi = *(const float4*)(gates + (size_t)s * G4_ + j4);
    const float4 gf = *(const float4*)(gates + (size_t)s * G4_ + 512 + j4);
    const float4 gg = *(const float4*)(gates + (size_t)s * G4_ + 1024 + j4);
    const float4 go = *(const float4*)(gates + (size_t)s * G4_ + 1536 + j4);
    const float4 bi0 = *(const float4*)(bih + j4);
    const float4 bi1 = *(const float4*)(bih + 512 + j4);
    const float4 bi2 = *(const float4*)(bih + 1024 + j4);
    const float4 bi3 = *(const float4*)(bih + 1536 + j4);
    const float4 bh0 = *(const float4*)(bhh + j4);
    const float4 bh1 = *(const float4*)(bhh + 512 + j4);
    const float4 bh2 = *(const float4*)(bhh + 1024 + j4);
    const float4 bh3 = *(const float4*)(bhh + 1536 + j4);

    float4 hv = *(float4*)(h + (size_t)s * H_ + j4);
    float4 cv = *(float4*)(c + (size_t)s * H_ + j4);
    float4 ov = *(float4*)(osum + (size_t)s * H_ + j4);

#define UPD(X)                                                                  \
    {                                                                           \
        const float I = sigmoidf_(gi.X + bi0.X + bh0.X);                        \
        const float F = sigmoidf_(gf.X + bi1.X + bh1.X);                        \
        const float G = fast_tanhf_(gg.X + bi2.X + bh2.X);                      \
        const float O = sigmoidf_(go.X + bi3.X + bh3.X);                        \
        const float cn = F * cv.X + I * G;                                      \
        const float hn = O * fast_tanhf_(cn);                                   \
        if (valid) { cv.X = cn; hv.X = hn; ov.X += hn; }                        \
    }
    UPD(x) UPD(y) UPD(z) UPD(w)
#undef UPD

    *(float4*)(h + (size_t)s * H_ + j4)    = hv;
    *(float4*)(c + (size_t)s * H_ + j4)    = cv;
    *(float4*)(osum + (size_t)s * H_ + j4) = ov;
}

// ---------------------------------------------------------------------------
// Final: scores = hsw @ Ww2t.T + bw2t + out_sum @ Wc2t.T + bc2t, log_softmax.
// One wave (64 threads = 64 tags) per position.
// ---------------------------------------------------------------------------
__global__ __launch_bounds__(64)
void scores_kernel(const float* __restrict__ hsw, const float* __restrict__ osum,
                   const float* __restrict__ Ww2t, const float* __restrict__ bw2t,
                   const float* __restrict__ Wc2t, const float* __restrict__ bc2t,
                   float* __restrict__ out)
{
    const int s = blockIdx.x;
    const int t = threadIdx.x;   // tag 0..63
    __shared__ float4 hrow[128], orow[128];
    hrow[t]      = ((const float4*)(hsw + (size_t)s * H_))[t];
    hrow[t + 64] = ((const float4*)(hsw + (size_t)s * H_))[t + 64];
    orow[t]      = ((const float4*)(osum + (size_t)s * H_))[t];
    orow[t + 64] = ((const float4*)(osum + (size_t)s * H_))[t + 64];
    __syncthreads();

    float acc = bw2t[t] + bc2t[t];
    const float4* w1 = (const float4*)(Ww2t + (size_t)t * H_);
    const float4* w2 = (const float4*)(Wc2t + (size_t)t * H_);
#pragma unroll 8
    for (int k = 0; k < 128; ++k) {
        const float4 a = w1[k], hb = hrow[k];
        acc = fmaf(a.x, hb.x, acc); acc = fmaf(a.y, hb.y, acc);
        acc = fmaf(a.z, hb.z, acc); acc = fmaf(a.w, hb.w, acc);
        const float4 b = w2[k], ob = orow[k];
        acc = fmaf(b.x, ob.x, acc); acc = fmaf(b.y, ob.y, acc);
        acc = fmaf(b.z, ob.z, acc); acc = fmaf(b.w, ob.w, acc);
    }
    float m = acc;
#pragma unroll
    for (int off = 32; off > 0; off >>= 1) m = fmaxf(m, __shfl_xor(m, off));
    float sum = __expf(acc - m);
#pragma unroll
    for (int off = 32; off > 0; off >>= 1) sum += __shfl_xor(sum, off);
    out[(size_t)s * T_ + t] = acc - m - __logf(sum);
}

// ---------------------------------------------------------------------------
extern "C" void kernel_launch(void* const* d_in, const int* in_sizes, int n_in,
                              void* d_out, int out_size, void* d_ws, size_t ws_size,
                              hipStream_t stream)
{
    (void)in_sizes; (void)n_in; (void)out_size; (void)ws_size;

    const int*   sent_in  = (const int*)d_in[0];
    const int*   char_in  = (const int*)d_in[1];
    const int*   lengths  = (const int*)d_in[2];
    const float* word_emb = (const float*)d_in[3];
    const float* char_emb = (const float*)d_in[4];
    const float* Wih_w    = (const float*)d_in[5];
    const float* Whh_w    = (const float*)d_in[6];
    const float* bih_w    = (const float*)d_in[7];
    const float* bhh_w    = (const float*)d_in[8];
    const float* Wih_c    = (const float*)d_in[9];
    const float* Whh_c    = (const float*)d_in[10];
    const float* bih_c    = (const float*)d_in[11];
    const float* bhh_c    = (const float*)d_in[12];
    const float* Ww2t     = (const float*)d_in[13];
    const float* bw2t     = (const float*)d_in[14];
    const float* Wc2t     = (const float*)d_in[15];
    const float* bc2t     = (const float*)d_in[16];

    // Workspace layout (bytes). gates aliases gxw: word phase completes first
    // (same-stream serialization).
    char* ws = (char*)d_ws;
    float* gxw  = (float*)(ws + 0);          // 4096*2048*4 = 33,554,432 (also char gates)
    float* hsw  = (float*)(ws + 33554432);   // 4096*512*4  =  8,388,608
    float* h_c  = (float*)(ws + 41943040);   //                8,388,608
    float* c_c  = (float*)(ws + 50331648);   //                8,388,608
    float* osum = (float*)(ws + 58720256);   //                8,388,608
    float* hbuf = (float*)(ws + 67108864);   // 2*512*4     =      4,096
    unsigned int* cnt = (unsigned int*)(ws + 67112960); // 4096*4 = 16,384
    // total: 67,129,344 bytes

    hipMemsetAsync(hbuf, 0, 4096, stream);
    hipMemsetAsync(cnt,  0, 16384, stream);
    hipMemsetAsync(h_c,  0, 8388608, stream);
    hipMemsetAsync(c_c,  0, 8388608, stream);
    hipMemsetAsync(osum, 0, 8388608, stream);

    const dim3 gemmGrid(G4_ / BN, S_ / BM);  // (16, 32)

    // --- word phase ---
    gemm_nt_kernel<<<gemmGrid, 256, 0, stream>>>(
        word_emb, sent_in, /*idxStride=*/1, /*idxOff=*/0, /*A2=*/nullptr,
        Wih_w, /*B2=*/nullptr, /*Ksplit=*/E_, /*K=*/E_, G4_, gxw);

    word_lstm_kernel<<<WORD_WGS, 512, 0, stream>>>(
        gxw, Whh_w, bih_w, bhh_w, hsw, hbuf, cnt, S_);

    // --- char phase: per step, fused [emb | h] @ [Wih | Whh].T then update ---
    for (int l = 0; l < L_; ++l) {
        gemm_nt_kernel<<<gemmGrid, 256, 0, stream>>>(
            char_emb, char_in, /*idxStride=*/L_, /*idxOff=*/l, /*A2=*/h_c,
            Wih_c, Whh_c, /*Ksplit=*/E_, /*K=*/E_ + H_, G4_, gxw /*gates*/);
        char_update_kernel<<<(S_ * 128) / 256, 256, 0, stream>>>(
            gxw, bih_c, bhh_c, lengths, l, h_c, c_c, osum);
    }

    // --- scores + log_softmax ---
    scores_kernel<<<S_, 64, 0, stream>>>(hsw, osum, Ww2t, bw2t, Wc2t, bc2t,
                                         (float*)d_out);
}

// Round 6
// 14878.841 us; speedup vs baseline: 1.0789x; 1.0789x over previous
//
#include <hip/hip_runtime.h>
#include <cstdint>
#include <cstddef>

// Problem constants
#define S_  4096   // sentence length / batch of positions
#define L_  16     // chars per word
#define E_  512    // embedding dim
#define H_  512    // hidden dim
#define G4_ 2048   // 4*H (gates)
#define T_  64     // tag count
#define WORD_WGS 32
#define CHAR_WGS 256
#define ALL_WGS  (WORD_WGS + CHAR_WGS)

__device__ __forceinline__ float sigmoidf_(float x) {
    return 1.0f / (1.0f + __expf(-x));
}
__device__ __forceinline__ float fast_tanhf_(float x) {
    return 1.0f - 2.0f / (__expf(2.0f * x) + 1.0f);
}

// ---------------------------------------------------------------------------
// fp32 GEMM for word gx:  C[m,n] = sum_k A1[idx(m)][k] * B1[n][k]
// (proven Round-5 kernel, A2 path retained but unused)
// ---------------------------------------------------------------------------
#define BM 128
#define BN 128
#define BK 16

__global__ __launch_bounds__(256, 2)
void gemm_nt_kernel(const float* __restrict__ A1, const int* __restrict__ idxA,
                    int idxStride, int idxOff, const float* __restrict__ A2,
                    const float* __restrict__ B1, const float* __restrict__ B2,
                    int Ksplit, int K, int N, float* __restrict__ C)
{
    __shared__ float As_[BK][BM + 4];
    __shared__ float Bs_[BK][BN + 4];
    __shared__ int   rIdx_[BM];

    const int tid = threadIdx.x;
    const int m0 = blockIdx.y * BM;
    const int n0 = blockIdx.x * BN;
    if (idxA && tid < BM)
        rIdx_[tid] = idxA[(size_t)(m0 + tid) * idxStride + idxOff];

    const int tx = tid & 15;
    const int ty = tid >> 4;
    const int ar = tid >> 2;
    const int aq = tid & 3;

    float acc[8][8];
#pragma unroll
    for (int i = 0; i < 8; ++i)
#pragma unroll
        for (int j = 0; j < 8; ++j) acc[i][j] = 0.f;

    for (int k0 = 0; k0 < K; k0 += BK) {
        __syncthreads();
        const bool firstHalf = (k0 < Ksplit);
        const int  kk0 = firstHalf ? k0 : (k0 - Ksplit);
#pragma unroll
        for (int part = 0; part < 2; ++part) {
            const int row = ar + part * 64;
            float4 av, bv;
            if (firstHalf) {
                const int grA = idxA ? rIdx_[row] : (m0 + row);
                av = *(const float4*)(A1 + (size_t)grA * Ksplit + kk0 + aq * 4);
                bv = *(const float4*)(B1 + (size_t)(n0 + row) * Ksplit + kk0 + aq * 4);
            } else {
                const int Kr = K - Ksplit;
                av = *(const float4*)(A2 + (size_t)(m0 + row) * Kr + kk0 + aq * 4);
                bv = *(const float4*)(B2 + (size_t)(n0 + row) * Kr + kk0 + aq * 4);
            }
            As_[aq * 4 + 0][row] = av.x; As_[aq * 4 + 1][row] = av.y;
            As_[aq * 4 + 2][row] = av.z; As_[aq * 4 + 3][row] = av.w;
            Bs_[aq * 4 + 0][row] = bv.x; Bs_[aq * 4 + 1][row] = bv.y;
            Bs_[aq * 4 + 2][row] = bv.z; Bs_[aq * 4 + 3][row] = bv.w;
        }
        __syncthreads();
#pragma unroll
        for (int kk = 0; kk < BK; ++kk) {
            const float4 a0 = *(const float4*)&As_[kk][ty * 4];
            const float4 a1 = *(const float4*)&As_[kk][64 + ty * 4];
            const float4 b0 = *(const float4*)&Bs_[kk][tx * 4];
            const float4 b1 = *(const float4*)&Bs_[kk][64 + tx * 4];
            const float a[8] = {a0.x, a0.y, a0.z, a0.w, a1.x, a1.y, a1.z, a1.w};
            const float b[8] = {b0.x, b0.y, b0.z, b0.w, b1.x, b1.y, b1.z, b1.w};
#pragma unroll
            for (int i = 0; i < 8; ++i)
#pragma unroll
                for (int j = 0; j < 8; ++j)
                    acc[i][j] = fmaf(a[i], b[j], acc[i][j]);
        }
    }
#pragma unroll
    for (int ri = 0; ri < 2; ++ri)
#pragma unroll
        for (int i = 0; i < 4; ++i) {
            const int m = m0 + ri * 64 + ty * 4 + i;
            float4 v0 = make_float4(acc[ri * 4 + i][0], acc[ri * 4 + i][1],
                                    acc[ri * 4 + i][2], acc[ri * 4 + i][3]);
            float4 v1 = make_float4(acc[ri * 4 + i][4], acc[ri * 4 + i][5],
                                    acc[ri * 4 + i][6], acc[ri * 4 + i][7]);
            *(float4*)(C + (size_t)m * N + n0 + tx * 4)      = v0;
            *(float4*)(C + (size_t)m * N + n0 + 64 + tx * 4) = v1;
        }
}

// ---------------------------------------------------------------------------
// Fused kernel: wgs 0..31 = word LSTM (proven path + w-reg pin + gx prefetch);
// wgs 32..287 = char LSTM, per-step GEMM fused with gate/c/h/osum update.
//
// Co-residency: __launch_bounds__(512,4) caps VGPR at 128 -> 16 waves/CU ->
// capacity 512 wgs of 512 thr; grid is 288. LDS 29.7 KB -> 2 wgs/CU. All wgs
// resident; spin barriers are deadlock-free.
//
// Char step structure (h_c WAR race excluded by two barriers):
//   stage+MAC (reads h_c, agent loads) -> barrier -> epilogue (writes h_c,
//   agent stores; c/osum wg-private plain) -> barrier.
// Char tile: 128 m-rows x 64 hidden units (B covers rows {g*512+hu},
// g=0..3 -> all four gates in-register -> no gates buffer).
// ---------------------------------------------------------------------------
__global__ __launch_bounds__(512, 4)
void fused_lstm_kernel(const float* __restrict__ gxw,
                       const float* __restrict__ Whh_w,
                       const float* __restrict__ bih_w,
                       const float* __restrict__ bhh_w,
                       float* __restrict__ hsw, float* __restrict__ h_buf,
                       unsigned int* __restrict__ cnt,
                       const int* __restrict__ char_in,
                       const int* __restrict__ lengths,
                       const float* __restrict__ char_emb,
                       const float* __restrict__ Wih_c,
                       const float* __restrict__ Whh_c,
                       const float* __restrict__ bih_c,
                       const float* __restrict__ bhh_c,
                       float* __restrict__ h_c, float* __restrict__ c_c,
                       float* __restrict__ osum)
{
    __shared__ float h_lds[512];        // word
    __shared__ float gate_lds[64];      // word
    __shared__ float wb[64];            // word bias sum
    __shared__ float As[16][132];       // char A tile [k][m]
    __shared__ float Bs[16][260];       // char B tile [k][g*64+u]
    __shared__ int   rIdx[128];         // char embedding gather rows
    __shared__ int   lens[128];         // char lengths
    __shared__ float cb[256];           // char bias sum [g*64+u]

    const int tid = threadIdx.x;

    if (blockIdx.x < WORD_WGS) {
        // ------------------------- word LSTM -------------------------
        const int wg   = blockIdx.x;
        const int base = wg * 16;
        const int r    = tid >> 3;
        const int p    = tid & 7;
        const int grow = (r >> 4) * 512 + base + (r & 15);

        // Whh slice pinned in registers (asm barrier: not rematerializable)
        float wreg[64];
        {
            const float4* Wrow = (const float4*)(Whh_w + (size_t)grow * 512);
#pragma unroll
            for (int kk = 0; kk < 16; ++kk) {
                const float4 v = Wrow[kk * 8 + p];
                wreg[kk * 4 + 0] = v.x; wreg[kk * 4 + 1] = v.y;
                wreg[kk * 4 + 2] = v.z; wreg[kk * 4 + 3] = v.w;
            }
#pragma unroll
            for (int i = 0; i < 64; ++i) asm volatile("" : "+v"(wreg[i]));
        }
        if (tid < 64) {
            const int gr = (tid >> 4) * 512 + base + (tid & 15);
            wb[tid] = bih_w[gr] + bhh_w[gr];
        }
        if (tid < 128) ((float4*)h_lds)[tid] = make_float4(0.f, 0.f, 0.f, 0.f);
        float cstate = 0.f;
        __syncthreads();

        float gxv = (p == 0) ? gxw[grow] : 0.f;   // gx for t=0
        for (int t = 0; t < S_; ++t) {
            // prefetch next step's gx (hidden under this step's work)
            float gxn = 0.f;
            if (p == 0 && t + 1 < S_) gxn = gxw[(size_t)(t + 1) * G4_ + grow];

            float s = 0.f;
#pragma unroll
            for (int kk = 0; kk < 16; ++kk) {
                const float4 h4 = ((const float4*)h_lds)[kk * 8 + p];
                s = fmaf(wreg[kk * 4 + 0], h4.x, s);
                s = fmaf(wreg[kk * 4 + 1], h4.y, s);
                s = fmaf(wreg[kk * 4 + 2], h4.z, s);
                s = fmaf(wreg[kk * 4 + 3], h4.w, s);
            }
            s += __shfl_xor(s, 1);
            s += __shfl_xor(s, 2);
            s += __shfl_xor(s, 4);
            if (p == 0) gate_lds[r] = s + gxv + wb[r];
            __syncthreads();

            if (tid < 16) {
                const float gi = gate_lds[tid];
                const float gf = gate_lds[16 + tid];
                const float gg = gate_lds[32 + tid];
                const float go = gate_lds[48 + tid];
                const float cn = sigmoidf_(gf) * cstate + sigmoidf_(gi) * fast_tanhf_(gg);
                cstate = cn;
                const float hn = sigmoidf_(go) * fast_tanhf_(cn);
                hsw[(size_t)t * H_ + base + tid] = hn;
                __hip_atomic_store(&h_buf[((t + 1) & 1) * H_ + base + tid], hn,
                                   __ATOMIC_RELAXED, __HIP_MEMORY_SCOPE_AGENT);
            }
            __syncthreads();   // drains vmcnt before release

            if (tid == 0) {
                __hip_atomic_fetch_add(&cnt[0], 1u, __ATOMIC_RELEASE,
                                       __HIP_MEMORY_SCOPE_AGENT);
                while (__hip_atomic_load(&cnt[0], __ATOMIC_ACQUIRE,
                                         __HIP_MEMORY_SCOPE_AGENT)
                       < (unsigned)WORD_WGS * (unsigned)(t + 1))
                    __builtin_amdgcn_s_sleep(2);
            }
            __syncthreads();

            h_lds[tid] = __hip_atomic_load(&h_buf[((t + 1) & 1) * H_ + tid],
                                           __ATOMIC_RELAXED, __HIP_MEMORY_SCOPE_AGENT);
            __syncthreads();
            gxv = gxn;
        }
    } else {
        // ------------------------- char LSTM -------------------------
        const int cw  = blockIdx.x - WORD_WGS;   // 0..255
        const int m0  = (cw >> 3) * 128;         // m-tile
        const int hu0 = (cw & 7) * 64;           // hidden-unit tile
        const int tx  = tid & 31;                // 0..31 (2 hidden units)
        const int ty  = tid >> 5;                // 0..15 (8 m-rows)

        if (tid < 128) lens[tid] = lengths[m0 + tid];
        if (tid < 256) {
            const int g = tid >> 6, ul = tid & 63;
            const int br = g * 512 + hu0 + ul;
            cb[tid] = bih_c[br] + bhh_c[br];
        }
        // (first kt-loop __syncthreads covers lens/cb/rIdx)

        for (int l = 0; l < L_; ++l) {
            if (tid < 128) rIdx[tid] = char_in[(size_t)(m0 + tid) * L_ + l];

            float acc[8][8];
#pragma unroll
            for (int i = 0; i < 8; ++i)
#pragma unroll
                for (int j = 0; j < 8; ++j) acc[i][j] = 0.f;

            for (int kt = 0; kt < 64; ++kt) {
                const int k0 = kt * 16;
                __syncthreads();
                const int row = tid >> 2, q = tid & 3;
                // A tile: [emb | h_c] row (m0+row), k-slice
                float4 av;
                if (k0 < 512) {
                    av = *(const float4*)(char_emb + (size_t)rIdx[row] * E_ + k0 + q * 4);
                } else {
                    const float* hp = h_c + (size_t)(m0 + row) * H_ + (k0 - 512) + q * 4;
                    av.x = __hip_atomic_load(hp + 0, __ATOMIC_RELAXED, __HIP_MEMORY_SCOPE_AGENT);
                    av.y = __hip_atomic_load(hp + 1, __ATOMIC_RELAXED, __HIP_MEMORY_SCOPE_AGENT);
                    av.z = __hip_atomic_load(hp + 2, __ATOMIC_RELAXED, __HIP_MEMORY_SCOPE_AGENT);
                    av.w = __hip_atomic_load(hp + 3, __ATOMIC_RELAXED, __HIP_MEMORY_SCOPE_AGENT);
                }
                As[q * 4 + 0][row] = av.x; As[q * 4 + 1][row] = av.y;
                As[q * 4 + 2][row] = av.z; As[q * 4 + 3][row] = av.w;
                // B tile: col c = g*64+u -> W row g*512 + hu0 + u
#pragma unroll
                for (int cc = 0; cc < 2; ++cc) {
                    const int c  = row + cc * 128;
                    const int g  = c >> 6, u = c & 63;
                    const int br = g * 512 + hu0 + u;
                    const float* bp = (k0 < 512)
                        ? (Wih_c + (size_t)br * E_ + k0 + q * 4)
                        : (Whh_c + (size_t)br * H_ + (k0 - 512) + q * 4);
                    const float4 bv = *(const float4*)bp;
                    Bs[q * 4 + 0][c] = bv.x; Bs[q * 4 + 1][c] = bv.y;
                    Bs[q * 4 + 2][c] = bv.z; Bs[q * 4 + 3][c] = bv.w;
                }
                __syncthreads();
#pragma unroll
                for (int kk = 0; kk < 16; ++kk) {
                    const float4 a0 = *(const float4*)&As[kk][ty * 8];
                    const float4 a1 = *(const float4*)&As[kk][ty * 8 + 4];
                    const float a[8] = {a0.x, a0.y, a0.z, a0.w, a1.x, a1.y, a1.z, a1.w};
                    float b[8];
#pragma unroll
                    for (int g = 0; g < 4; ++g) {
                        const float2 bg = *(const float2*)&Bs[kk][g * 64 + 2 * tx];
                        b[(g << 1)]     = bg.x;
                        b[(g << 1) | 1] = bg.y;
                    }
#pragma unroll
                    for (int i = 0; i < 8; ++i)
#pragma unroll
                        for (int j = 0; j < 8; ++j)
                            acc[i][j] = fmaf(a[i], b[j], acc[i][j]);
                }
            }

            // barrier #1: all wgs finished READING h_c for this step
            __syncthreads();
            if (tid == 0) {
                __hip_atomic_fetch_add(&cnt[32], 1u, __ATOMIC_RELEASE,
                                       __HIP_MEMORY_SCOPE_AGENT);
                while (__hip_atomic_load(&cnt[32], __ATOMIC_ACQUIRE,
                                         __HIP_MEMORY_SCOPE_AGENT)
                       < (unsigned)CHAR_WGS * (unsigned)(2 * l + 1))
                    __builtin_amdgcn_s_sleep(2);
            }
            __syncthreads();

            // epilogue: gates -> c,h,osum (skip-store freezes masked rows)
#pragma unroll
            for (int i = 0; i < 8; ++i) {
                const int mr = ty * 8 + i;
                const int m  = m0 + mr;
                if (l < lens[mr]) {
                    const int hl = 2 * tx;
                    float* cp = c_c  + (size_t)m * H_ + hu0 + hl;
                    float* op = osum + (size_t)m * H_ + hu0 + hl;
                    float2 c2 = *(float2*)cp;
                    float2 o2 = *(float2*)op;
#pragma unroll
                    for (int u = 0; u < 2; ++u) {
                        const float I = sigmoidf_(acc[i][0 + u] + cb[      hl + u]);
                        const float F = sigmoidf_(acc[i][2 + u] + cb[ 64 + hl + u]);
                        const float G = fast_tanhf_(acc[i][4 + u] + cb[128 + hl + u]);
                        const float O = sigmoidf_(acc[i][6 + u] + cb[192 + hl + u]);
                        const float cv = u ? c2.y : c2.x;
                        const float cn = F * cv + I * G;
                        const float hn = O * fast_tanhf_(cn);
                        if (u) { c2.y = cn; o2.y += hn; } else { c2.x = cn; o2.x += hn; }
                        __hip_atomic_store(h_c + (size_t)m * H_ + hu0 + hl + u, hn,
                                           __ATOMIC_RELAXED, __HIP_MEMORY_SCOPE_AGENT);
                    }
                    *(float2*)cp = c2;
                    *(float2*)op = o2;
                }
            }

            // barrier #2: all h_c writes done before next step's reads
            __syncthreads();
            if (tid == 0) {
                __hip_atomic_fetch_add(&cnt[32], 1u, __ATOMIC_RELEASE,
                                       __HIP_MEMORY_SCOPE_AGENT);
                while (__hip_atomic_load(&cnt[32], __ATOMIC_ACQUIRE,
                                         __HIP_MEMORY_SCOPE_AGENT)
                       < (unsigned)CHAR_WGS * (unsigned)(2 * l + 2))
                    __builtin_amdgcn_s_sleep(2);
            }
            __syncthreads();
        }
    }
}

// ---------------------------------------------------------------------------
// scores + log_softmax (unchanged, proven)
// ---------------------------------------------------------------------------
__global__ __launch_bounds__(64)
void scores_kernel(const float* __restrict__ hsw, const float* __restrict__ osum,
                   const float* __restrict__ Ww2t, const float* __restrict__ bw2t,
                   const float* __restrict__ Wc2t, const float* __restrict__ bc2t,
                   float* __restrict__ out)
{
    const int s = blockIdx.x;
    const int t = threadIdx.x;
    __shared__ float4 hrow[128], orow[128];
    hrow[t]      = ((const float4*)(hsw + (size_t)s * H_))[t];
    hrow[t + 64] = ((const float4*)(hsw + (size_t)s * H_))[t + 64];
    orow[t]      = ((const float4*)(osum + (size_t)s * H_))[t];
    orow[t + 64] = ((const float4*)(osum + (size_t)s * H_))[t + 64];
    __syncthreads();

    float acc = bw2t[t] + bc2t[t];
    const float4* w1 = (const float4*)(Ww2t + (size_t)t * H_);
    const float4* w2 = (const float4*)(Wc2t + (size_t)t * H_);
#pragma unroll 8
    for (int k = 0; k < 128; ++k) {
        const float4 a = w1[k], hb = hrow[k];
        acc = fmaf(a.x, hb.x, acc); acc = fmaf(a.y, hb.y, acc);
        acc = fmaf(a.z, hb.z, acc); acc = fmaf(a.w, hb.w, acc);
        const float4 b = w2[k], ob = orow[k];
        acc = fmaf(b.x, ob.x, acc); acc = fmaf(b.y, ob.y, acc);
        acc = fmaf(b.z, ob.z, acc); acc = fmaf(b.w, ob.w, acc);
    }
    float m = acc;
#pragma unroll
    for (int off = 32; off > 0; off >>= 1) m = fmaxf(m, __shfl_xor(m, off));
    float sum = __expf(acc - m);
#pragma unroll
    for (int off = 32; off > 0; off >>= 1) sum += __shfl_xor(sum, off);
    out[(size_t)s * T_ + t] = acc - m - __logf(sum);
}

// ---------------------------------------------------------------------------
extern "C" void kernel_launch(void* const* d_in, const int* in_sizes, int n_in,
                              void* d_out, int out_size, void* d_ws, size_t ws_size,
                              hipStream_t stream)
{
    (void)in_sizes; (void)n_in; (void)out_size; (void)ws_size;

    const int*   sent_in  = (const int*)d_in[0];
    const int*   char_in  = (const int*)d_in[1];
    const int*   lengths  = (const int*)d_in[2];
    const float* word_emb = (const float*)d_in[3];
    const float* char_emb = (const float*)d_in[4];
    const float* Wih_w    = (const float*)d_in[5];
    const float* Whh_w    = (const float*)d_in[6];
    const float* bih_w    = (const float*)d_in[7];
    const float* bhh_w    = (const float*)d_in[8];
    const float* Wih_c    = (const float*)d_in[9];
    const float* Whh_c    = (const float*)d_in[10];
    const float* bih_c    = (const float*)d_in[11];
    const float* bhh_c    = (const float*)d_in[12];
    const float* Ww2t     = (const float*)d_in[13];
    const float* bw2t     = (const float*)d_in[14];
    const float* Wc2t     = (const float*)d_in[15];
    const float* bc2t     = (const float*)d_in[16];

    // Workspace layout (bytes), identical footprint to the passing run.
    char* ws = (char*)d_ws;
    float* gxw  = (float*)(ws + 0);          // 4096*2048*4 = 33,554,432
    float* hsw  = (float*)(ws + 33554432);   // 8,388,608
    float* h_c  = (float*)(ws + 41943040);   // 8,388,608
    float* c_c  = (float*)(ws + 50331648);   // 8,388,608
    float* osum = (float*)(ws + 58720256);   // 8,388,608
    float* hbuf = (float*)(ws + 67108864);   // 4,096
    unsigned int* cnt = (unsigned int*)(ws + 67112960); // 16,384
    // cnt[0] = word barrier counter (monotone), cnt[32] = char (separate line)

    hipMemsetAsync(hbuf, 0, 4096, stream);
    hipMemsetAsync(cnt,  0, 16384, stream);
    hipMemsetAsync(h_c,  0, 8388608, stream);
    hipMemsetAsync(c_c,  0, 8388608, stream);
    hipMemsetAsync(osum, 0, 8388608, stream);

    // word gx GEMM (must precede fused kernel)
    const dim3 gemmGrid(G4_ / BN, S_ / BM);
    gemm_nt_kernel<<<gemmGrid, 256, 0, stream>>>(
        word_emb, sent_in, /*idxStride=*/1, /*idxOff=*/0, /*A2=*/nullptr,
        Wih_w, /*B2=*/nullptr, /*Ksplit=*/E_, /*K=*/E_, G4_, gxw);

    // fused word LSTM || char LSTM
    fused_lstm_kernel<<<ALL_WGS, 512, 0, stream>>>(
        gxw, Whh_w, bih_w, bhh_w, hsw, hbuf, cnt,
        char_in, lengths, char_emb, Wih_c, Whh_c, bih_c, bhh_c,
        h_c, c_c, osum);

    // scores + log_softmax
    scores_kernel<<<S_, 64, 0, stream>>>(hsw, osum, Ww2t, bw2t, Wc2t, bc2t,
                                         (float*)d_out);
}